// Round 1
// 176.072 us; speedup vs baseline: 1.0406x; 1.0406x over previous
//
#include <hip/hip_runtime.h>
#include <hip/hip_bf16.h>
#include <math.h>

#define BATCH 16
#define NPTS 10000
#define HID 128
#define NOUT 5
#define TM 64
#define TPB 256

typedef unsigned short ushort_t;
typedef __attribute__((ext_vector_type(8))) short short8;      // 8 bf16 = 4 VGPRs
typedef __attribute__((ext_vector_type(4))) float f32x4;       // MFMA C/D

__device__ __forceinline__ float fast_tanh(float x) {
    // tanh(x) = 1 - 2/(e^{2x}+1); v_rcp_f32 (1 ulp) instead of precise div.
    float e = __expf(2.0f * x);
    return 1.0f - 2.0f * __builtin_amdgcn_rcpf(e + 1.0f);
}
__device__ __forceinline__ float rowdy_act(float x, float a, float w) {
    return fast_tanh(x) + a * __sinf(w * x);
}
__device__ __forceinline__ ushort_t f32_to_bf16_rn(float f) {
    unsigned u = __float_as_uint(f);
    unsigned r = (u + 0x7FFFu + ((u >> 16) & 1u)) >> 16;
    return (ushort_t)r;
}
__device__ __forceinline__ float bf16_to_f32(ushort_t u) {
    return __uint_as_float(((unsigned)u) << 16);
}

// XOR bank-swizzle for the xfh/xfl tiles. Byte-level: byte ^= ((byte>>3)&0x30)
// (bank bits 4,5 ^= lane-entropy bits 7,8). Consistent pair:
//   short index: s ^ ((s>>3)&0x18);  16B-vector index: v ^ ((v>>3)&3)
// Identity: swzs(8v+k) == 8*swzv(v)+k, so b128 producers/consumers and b16
// scatter stores all see the same bijection. Kills the 8-way conflict on the
// layer-epilogue ds_write_b16 (was: banks = {jlow>>1, r(fixed), quad&1} = 8
// banks x 8 lanes; now 32 banks x 2 lanes = free).
__device__ __forceinline__ int swzv(int v) { return v ^ ((v >> 3) & 3); }
__device__ __forceinline__ int swzs(int s) { return s ^ ((s >> 3) & 0x18); }

// ============ Fused prep (blocks 0-2) + branch (blocks 3-18) ============
// Branch rewritten for latency: one HBM round trip per phase is hidden by
// register prefetch of the NEXT phase's weight tile (A/B ping-pong, all
// indices compile-time so the arrays stay in VGPRs); all per-j scalar
// constants (ab/wb/bb0/bbv/bbf/btf) loaded once at entry; bcomb done as a
// per-chunk wave-shuffle reduction instead of a 128-iter serial global loop.
__global__ __launch_bounds__(256, 1) void prep_branch_kernel(
    const float* __restrict__ Wt, ushort_t* __restrict__ whi, ushort_t* __restrict__ wlo,
    const float* __restrict__ params, const float* __restrict__ Wb0, const float* __restrict__ bb0,
    const float* __restrict__ Wb, const float* __restrict__ bbv,
    const float* __restrict__ Wbf, const float* __restrict__ bbf,
    const float* __restrict__ ab, const float* __restrict__ wb,
    const float* __restrict__ Wtf, const float* __restrict__ btf,
    float* __restrict__ g_gates, float* __restrict__ g_wcomb, float* __restrict__ g_bcomb)
{
    __shared__ __align__(16) float wsh[HID * HID];   // 64 KB (prep staging)
    __shared__ __align__(16) float hbuf[HID];
    __shared__ __align__(16) float pred[8 * HID];    // 8-way k-split partials
    __shared__ __align__(16) float bcbuf[NOUT * HID];
    __shared__ __align__(16) float wcred[2 * NOUT * HID];
    __shared__ __align__(16) float btfs[HID];
    __shared__ float bred[NOUT][2];

    const int tid = threadIdx.x;

    if (blockIdx.x < 3) {
        // ---------------- prep: one block per trunk layer (unchanged) ----------------
        const int l = blockIdx.x;
        const float4* src = (const float4*)(Wt + l * HID * HID);
        #pragma unroll
        for (int i = 0; i < 16; i++)
            ((float4*)wsh)[i * 256 + tid] = src[i * 256 + tid];
        __syncthreads();
        for (int e = tid; e < 2048; e += 256) {
            int t = e >> 8, s = (e >> 6) & 3, lam = e & 63;
            int k0 = s * 32 + (lam >> 4) * 8;
            int n = t * 16 + (lam & 15);
            short8 h8, l8;
            #pragma unroll
            for (int j = 0; j < 8; j++) {
                float v = wsh[(k0 + j) * HID + n];
                ushort_t h = f32_to_bf16_rn(v);
                float rem = v - bf16_to_f32(h);
                h8[j] = (short)h;
                l8[j] = (short)f32_to_bf16_rn(rem);
            }
            ((short8*)whi)[l * 2048 + e] = h8;
            ((short8*)wlo)[l * 2048 + e] = l8;
        }
        return;
    }

    // ---------------- branch: one block per batch ----------------
    const int b = blockIdx.x - 3;
    const int j = tid & 127;
    const bool act = (tid < 128);
    const int jg = tid & 31;
    const int ks = tid >> 5;
    const int wv = tid >> 6;                 // wave id 0..3

    // ---- hoisted constant loads: all issued up front, independent ----
    float abr[4], wbr[4];
    #pragma unroll
    for (int l = 0; l < 4; l++) { abr[l] = ab[l * HID + j]; wbr[l] = wb[l * HID + j]; }
    float bb0r = bb0[j];
    float bbvr[3];
    #pragma unroll
    for (int i = 0; i < 3; i++) bbvr[i] = bbv[i * HID + j];
    float bbfr[NOUT];
    #pragma unroll
    for (int o = 0; o < NOUT; o++) bbfr[o] = bbf[o * HID + j];
    float p6[6], w0r[6];
    #pragma unroll
    for (int k = 0; k < 6; k++) { p6[k] = params[b * 6 + k]; w0r[k] = Wb0[k * HID + j]; }
    if (act) btfs[j] = btf[j];

    // ---- weight tile ping-pong registers (static indexing only) ----
    float4 A[16], Bv[16];
    {   // prefetch layer-0 (Wb[0]) into A before L0 compute
        const float4* W4 = (const float4*)Wb;
        #pragma unroll
        for (int kk = 0; kk < 16; kk++) A[kk] = W4[(ks * 16 + kk) * 32 + jg];
    }

    // L0 (K=6): all threads redundant on j
    float g;
    {
        float z = bb0r;
        #pragma unroll
        for (int k = 0; k < 6; k++) z += p6[k] * w0r[k];
        float h = rowdy_act(z, abr[0], wbr[0]);
        if (act) { g_gates[b * 4 * HID + j] = h; hbuf[j] = h; }
        g = h;                                // gate[0] (act threads only use it)
    }
    __syncthreads();

    // hidden layer: MAC from CUR regs -> pred -> sync -> reduce+rowdy -> hbuf -> sync
#define BR_LAYER(CUR, I) { \
        float4 acc = make_float4(0.f, 0.f, 0.f, 0.f); \
        _Pragma("unroll") \
        for (int kk = 0; kk < 16; kk++) { \
            float hv = hbuf[ks * 16 + kk]; \
            acc.x += hv * CUR[kk].x; acc.y += hv * CUR[kk].y; \
            acc.z += hv * CUR[kk].z; acc.w += hv * CUR[kk].w; \
        } \
        *(float4*)&pred[ks * HID + 4 * jg] = acc; \
        __syncthreads(); \
        if (act) { \
            float zz = bbvr[I]; \
            _Pragma("unroll") \
            for (int s = 0; s < 8; s++) zz += pred[s * HID + j]; \
            float hn = rowdy_act(zz, abr[(I) + 1], wbr[(I) + 1]); \
            g += hn; \
            g_gates[b * 4 * HID + ((I) + 1) * HID + j] = g; \
            hbuf[j] = hn; \
        } \
        __syncthreads(); }

    // branch_out chunk: MAC -> pred -> sync -> reduce -> bcbuf + bcomb shuffle-reduce
#define BR_CHUNK(CUR, O) { \
        float4 acc = make_float4(0.f, 0.f, 0.f, 0.f); \
        _Pragma("unroll") \
        for (int kk = 0; kk < 16; kk++) { \
            float hv = hbuf[ks * 16 + kk]; \
            acc.x += hv * CUR[kk].x; acc.y += hv * CUR[kk].y; \
            acc.z += hv * CUR[kk].z; acc.w += hv * CUR[kk].w; \
        } \
        *(float4*)&pred[ks * HID + 4 * jg] = acc; \
        __syncthreads(); \
        if (act) { \
            float s = bbfr[O]; \
            _Pragma("unroll") \
            for (int sI = 0; sI < 8; sI++) s += pred[sI * HID + j]; \
            bcbuf[(O) * HID + j] = s; \
            float pp = btfs[j] * s; \
            _Pragma("unroll") \
            for (int off = 32; off >= 1; off >>= 1) pp += __shfl_xor(pp, off, 64); \
            if ((tid & 63) == 0) bred[O][wv] = pp; \
        } \
        __syncthreads(); }

#define PF_WB(DST, I) { const float4* W4 = (const float4*)(Wb + (I) * HID * HID); \
        _Pragma("unroll") \
        for (int kk = 0; kk < 16; kk++) DST[kk] = W4[(ks * 16 + kk) * 32 + jg]; }
#define PF_BF(DST, O) { const float4* W4 = (const float4*)Wbf; \
        _Pragma("unroll") \
        for (int kk = 0; kk < 16; kk++) DST[kk] = W4[(ks * 16 + kk) * 160 + (O) * 32 + jg]; }

    // 3 hidden layers, prefetching the next tile while computing the current
    PF_WB(Bv, 1)  BR_LAYER(A, 0)
    PF_WB(A, 2)   BR_LAYER(Bv, 1)
    PF_BF(Bv, 0)  BR_LAYER(A, 2)

    // 5 output chunks of Wbf (K=128)
    PF_BF(A, 1)   BR_CHUNK(Bv, 0)
    PF_BF(Bv, 2)  BR_CHUNK(A, 1)
    PF_BF(A, 3)   BR_CHUNK(Bv, 2)
    PF_BF(Bv, 4)  BR_CHUNK(A, 3)
    // prefetch Wtf (wcomb mapping) into A, then last chunk
    const int jj = tid & 127;
    const int hs = tid >> 7;                 // 0/1 half of h
    {
        const float4* Wtf4 = (const float4*)Wtf;
        #pragma unroll
        for (int kk = 0; kk < 16; kk++) A[kk] = Wtf4[jj * 32 + hs * 16 + kk];
    }
    BR_CHUNK(Bv, 4)

    // Wcomb[b][j][o] = sum_h Wtf[j][h] * bc[o][h]; Wtf already in A regs
    {
        float wc[NOUT] = {0.f, 0.f, 0.f, 0.f, 0.f};
        #pragma unroll
        for (int h4 = 0; h4 < 16; h4++) {
            float4 wvv = A[h4];
            int h2 = hs * 64 + h4 * 4;
            #pragma unroll
            for (int o = 0; o < NOUT; o++) {
                float4 bv = *(const float4*)&bcbuf[o * HID + h2];
                wc[o] += wvv.x * bv.x + wvv.y * bv.y + wvv.z * bv.z + wvv.w * bv.w;
            }
        }
        #pragma unroll
        for (int o = 0; o < NOUT; o++) wcred[(hs * NOUT + o) * HID + jj] = wc[o];
        __syncthreads();
        if (act) {
            #pragma unroll
            for (int o = 0; o < NOUT; o++)
                g_wcomb[b * HID * NOUT + jj * NOUT + o] =
                    wcred[o * HID + jj] + wcred[(NOUT + o) * HID + jj];
        }
        if (tid < NOUT) g_bcomb[b * NOUT + tid] = bred[tid][0] + bred[tid][1];
    }
#undef BR_LAYER
#undef BR_CHUNK
#undef PF_WB
#undef PF_BF
}

// ============ Trunk kernel: round-6 structure + xf bank swizzle ============
__global__ __launch_bounds__(TPB, 3) void trunk_kernel(
    const float* __restrict__ coords, const float* __restrict__ sdf,
    const float* __restrict__ Wt0, const float* __restrict__ bt0,
    const float* __restrict__ bt, const float* __restrict__ at, const float* __restrict__ wt,
    const float* __restrict__ g_gates, const float* __restrict__ g_wcomb,
    const float* __restrict__ g_bcomb,
    const ushort_t* __restrict__ whi, const ushort_t* __restrict__ wlo,
    float* __restrict__ out)
{
    __shared__ __align__(16) ushort_t xfh[TM * HID];            // 16 KB bf16 hi (swizzled)
    __shared__ __align__(16) ushort_t xfl[TM * HID];            // 16 KB bf16 lo (swizzled)
    __shared__ __align__(16) float sb_bias[4][HID];
    __shared__ __align__(16) float sb_a[4][HID];
    __shared__ __align__(16) float sb_w[4][HID];
    __shared__ __align__(16) float sb_g[4][HID];
    __shared__ __align__(16) float Wt0s[4][HID];
    __shared__ __align__(16) float Wc[NOUT][HID];
    __shared__ float bcs[NOUT];
    __shared__ __align__(16) float xin[TM][4];
    __shared__ float redbuf[4][TM][NOUT];

    const int b = blockIdx.y;
    const int p0 = blockIdx.x * TM;
    const int tid = threadIdx.x;
    const int w = tid >> 6;
    const int lam = tid & 63;
    const int quad = lam >> 4, lq = lam & 15;

    for (int idx = tid; idx < 4 * HID; idx += TPB) {
        int l = idx >> 7, jj = idx & (HID - 1);
        sb_bias[l][jj] = (l == 0) ? bt0[jj] : bt[(l - 1) * HID + jj];
        sb_a[l][jj] = at[idx];
        sb_w[l][jj] = wt[idx];
        sb_g[l][jj] = g_gates[b * 4 * HID + idx];
        Wt0s[l][jj] = Wt0[idx];
    }
    for (int idx = tid; idx < HID * NOUT; idx += TPB) {
        int k = idx / NOUT, o = idx - k * NOUT;
        Wc[o][k] = g_wcomb[b * HID * NOUT + idx];
    }
    if (tid < NOUT) bcs[tid] = g_bcomb[b * NOUT + tid];

    if (tid < 192) {
        int p = tid / 3, c = tid - p * 3;
        int gp = p0 + p;
        xin[p][c] = (gp < NPTS) ? coords[(size_t)(b * NPTS + gp) * 3 + c] : 0.0f;
    } else {
        int p = tid - 192;
        int gp = p0 + p;
        xin[p][3] = (gp < NPTS) ? sdf[b * NPTS + gp] : 0.0f;
    }
    __syncthreads();

    {
        const int s = w;
        float w0c[8], w1c[8], w2c[8], w3c[8], bc8[8], ac[8], wc8[8], gc[8];
        #pragma unroll
        for (int jj = 0; jj < 8; jj++) {
            int col = s * 32 + quad * 8 + jj;
            w0c[jj] = Wt0s[0][col];
            w1c[jj] = Wt0s[1][col];
            w2c[jj] = Wt0s[2][col];
            w3c[jj] = Wt0s[3][col];
            bc8[jj] = sb_bias[0][col];
            ac[jj] = sb_a[0][col];
            wc8[jj] = sb_w[0][col];
            gc[jj] = sb_g[0][col];
        }
        #pragma unroll
        for (int mt = 0; mt < 4; mt++) {
            int row = mt * 16 + lq;
            float4 xi = *(const float4*)&xin[row][0];
            float y[8];
            #pragma unroll
            for (int jj = 0; jj < 8; jj++) {
                float zv = xi.x * w0c[jj] + xi.y * w1c[jj] + xi.z * w2c[jj] + xi.w * w3c[jj] + bc8[jj];
                y[jj] = rowdy_act(zv, ac[jj], wc8[jj]) * gc[jj];
            }
            uint4 hp, lp;
            unsigned* hpp = (unsigned*)&hp;
            unsigned* lpp = (unsigned*)&lp;
            #pragma unroll
            for (int pr = 0; pr < 4; pr++) {
                unsigned ue = __float_as_uint(y[2 * pr]);
                unsigned uo = __float_as_uint(y[2 * pr + 1]);
                hpp[pr] = (ue >> 16) | (uo & 0xFFFF0000u);
                float le = y[2 * pr] - __uint_as_float(ue & 0xFFFF0000u);
                float lo_ = y[2 * pr + 1] - __uint_as_float(uo & 0xFFFF0000u);
                lpp[pr] = (__float_as_uint(le) >> 16) | (__float_as_uint(lo_) & 0xFFFF0000u);
            }
            int vdst = swzv((mt * 4 + s) * 64 + lam) * 8;
            *(uint4*)&xfh[vdst] = hp;
            *(uint4*)&xfl[vdst] = lp;
        }
    }
    __syncthreads();

    const short8* Wh8 = (const short8*)whi;
    const short8* Wl8 = (const short8*)wlo;
    const int lq3 = lq >> 3;
    const int jlow = lq & 7;
    const int ebase0 = w * 512 + (lq3 * 16 + quad * 4) * 8 + jlow;          // nt = 2w
    const int ebase1 = w * 512 + ((2 + lq3) * 16 + quad * 4) * 8 + jlow;    // nt = 2w+1
    const int n0 = 32 * w + lq, n1 = 32 * w + 16 + lq;

    for (int l = 1; l <= 3; l++) {
        const int fb = (l - 1) * 32;
        float b0 = sb_bias[l][n0], b1 = sb_bias[l][n1];
        f32x4 acc[4][2];
        #pragma unroll
        for (int mt = 0; mt < 4; mt++) {
            acc[mt][0] = (f32x4){b0, b0, b0, b0};
            acc[mt][1] = (f32x4){b1, b1, b1, b1};
        }
        for (int s = 0; s < 4; s++) {
            short8 bh0 = Wh8[(size_t)(fb + (2 * w) * 4 + s) * 64 + lam];
            short8 bl0 = Wl8[(size_t)(fb + (2 * w) * 4 + s) * 64 + lam];
            short8 bh1 = Wh8[(size_t)(fb + (2 * w + 1) * 4 + s) * 64 + lam];
            short8 bl1 = Wl8[(size_t)(fb + (2 * w + 1) * 4 + s) * 64 + lam];
            #pragma unroll
            for (int mt = 0; mt < 4; mt++) {
                int vsrc = swzv((mt * 4 + s) * 64 + lam) * 8;
                short8 ah = *(const short8*)&xfh[vsrc];
                short8 al = *(const short8*)&xfl[vsrc];
                acc[mt][0] = __builtin_amdgcn_mfma_f32_16x16x32_bf16(ah, bh0, acc[mt][0], 0, 0, 0);
                acc[mt][0] = __builtin_amdgcn_mfma_f32_16x16x32_bf16(al, bh0, acc[mt][0], 0, 0, 0);
                acc[mt][0] = __builtin_amdgcn_mfma_f32_16x16x32_bf16(ah, bl0, acc[mt][0], 0, 0, 0);
                acc[mt][1] = __builtin_amdgcn_mfma_f32_16x16x32_bf16(ah, bh1, acc[mt][1], 0, 0, 0);
                acc[mt][1] = __builtin_amdgcn_mfma_f32_16x16x32_bf16(al, bh1, acc[mt][1], 0, 0, 0);
                acc[mt][1] = __builtin_amdgcn_mfma_f32_16x16x32_bf16(ah, bl1, acc[mt][1], 0, 0, 0);
            }
        }
        __syncthreads();
        float a0 = sb_a[l][n0], ww0 = sb_w[l][n0], gg0 = sb_g[l][n0];
        float a1 = sb_a[l][n1], ww1 = sb_w[l][n1], gg1 = sb_g[l][n1];
        #pragma unroll
        for (int mt = 0; mt < 4; mt++) {
            #pragma unroll
            for (int r = 0; r < 4; r++) {
                float y0 = rowdy_act(acc[mt][0][r], a0, ww0) * gg0;
                float y1 = rowdy_act(acc[mt][1][r], a1, ww1) * gg1;
                unsigned u0 = __float_as_uint(y0);
                unsigned u1 = __float_as_uint(y1);
                float l0f = y0 - __uint_as_float(u0 & 0xFFFF0000u);
                float l1f = y1 - __uint_as_float(u1 & 0xFFFF0000u);
                int i0 = swzs(mt * 2048 + ebase0 + r * 8);
                int i1 = swzs(mt * 2048 + ebase1 + r * 8);
                xfh[i0] = (ushort_t)(u0 >> 16);
                xfl[i0] = (ushort_t)(__float_as_uint(l0f) >> 16);
                xfh[i1] = (ushort_t)(u1 >> 16);
                xfl[i1] = (ushort_t)(__float_as_uint(l1f) >> 16);
            }
        }
        __syncthreads();
    }

    {
        int q = tid & 3, p = tid >> 2;
        int mt = p >> 4, prow = p & 15;
        float part[NOUT] = {0.f, 0.f, 0.f, 0.f, 0.f};
        #pragma unroll
        for (int g8 = 0; g8 < 4; g8++) {
            int base = swzv((mt * 4 + q) * 64 + g8 * 16 + prow) * 8;
            uint4 h4 = *(const uint4*)&xfh[base];
            uint4 l4 = *(const uint4*)&xfl[base];
            const unsigned* hu = (const unsigned*)&h4;
            const unsigned* lu = (const unsigned*)&l4;
            int c0 = q * 32 + g8 * 8;
            float xv[8];
            #pragma unroll
            for (int pr = 0; pr < 4; pr++) {
                xv[2 * pr]     = __uint_as_float(hu[pr] << 16) + __uint_as_float(lu[pr] << 16);
                xv[2 * pr + 1] = __uint_as_float(hu[pr] & 0xFFFF0000u) + __uint_as_float(lu[pr] & 0xFFFF0000u);
            }
            #pragma unroll
            for (int o = 0; o < NOUT; o++) {
                float4 wa = *(const float4*)&Wc[o][c0];
                float4 wb4 = *(const float4*)&Wc[o][c0 + 4];
                part[o] += xv[0] * wa.x + xv[1] * wa.y + xv[2] * wa.z + xv[3] * wa.w
                         + xv[4] * wb4.x + xv[5] * wb4.y + xv[6] * wb4.z + xv[7] * wb4.w;
            }
        }
        #pragma unroll
        for (int o = 0; o < NOUT; o++) redbuf[q][p][o] = part[o];
    }
    __syncthreads();
    if (tid < TM) {
        int gp = p0 + tid;
        if (gp < NPTS) {
            #pragma unroll
            for (int o = 0; o < NOUT; o++) {
                float s = bcs[o] + redbuf[0][tid][o] + redbuf[1][tid][o]
                                 + redbuf[2][tid][o] + redbuf[3][tid][o];
                out[(size_t)(b * NPTS + gp) * NOUT + o] = s;
            }
        }
    }
}

extern "C" void kernel_launch(void* const* d_in, const int* in_sizes, int n_in,
                              void* d_out, int out_size, void* d_ws, size_t ws_size,
                              hipStream_t stream) {
    (void)in_sizes; (void)n_in; (void)out_size; (void)ws_size;
    const float* coords = (const float*)d_in[0];
    const float* sdf    = (const float*)d_in[1];
    const float* params = (const float*)d_in[2];
    const float* Wb0    = (const float*)d_in[3];
    const float* bb0    = (const float*)d_in[4];
    const float* Wb     = (const float*)d_in[5];
    const float* bbv    = (const float*)d_in[6];
    const float* Wbf    = (const float*)d_in[7];
    const float* bbf    = (const float*)d_in[8];
    const float* ab     = (const float*)d_in[9];
    const float* wb     = (const float*)d_in[10];
    const float* Wt0    = (const float*)d_in[11];
    const float* bt0    = (const float*)d_in[12];
    const float* Wt     = (const float*)d_in[13];
    const float* bt     = (const float*)d_in[14];
    const float* Wtf    = (const float*)d_in[15];
    const float* btf    = (const float*)d_in[16];
    const float* at     = (const float*)d_in[17];
    const float* wt     = (const float*)d_in[18];
    float* out = (float*)d_out;
    float* ws  = (float*)d_ws;

    float* g_gates = ws;                        // 8192 floats
    float* g_wcomb = ws + 8192;                 // 10240 floats
    float* g_bcomb = ws + 8192 + 10240;         // 80 floats
    ushort_t* whi = (ushort_t*)(ws + 18512);    // 49152 bf16
    ushort_t* wlo = whi + 3 * HID * HID;        // 49152 bf16

    hipLaunchKernelGGL(prep_branch_kernel, dim3(19), dim3(256), 0, stream,
                       Wt, whi, wlo,
                       params, Wb0, bb0, Wb, bbv, Wbf, bbf, ab, wb, Wtf, btf,
                       g_gates, g_wcomb, g_bcomb);

    dim3 grid((NPTS + TM - 1) / TM, BATCH);
    hipLaunchKernelGGL(trunk_kernel, grid, dim3(TPB), 0, stream,
                       coords, sdf, Wt0, bt0, bt, at, wt,
                       g_gates, g_wcomb, g_bcomb, whi, wlo, out);
}

// Round 4
// 171.747 us; speedup vs baseline: 1.0668x; 1.0252x over previous
//
#include <hip/hip_runtime.h>
#include <hip/hip_bf16.h>
#include <math.h>

#define BATCH 16
#define NPTS 10000
#define HID 128
#define NOUT 5
#define TM 64
#define TPB 256

typedef unsigned short ushort_t;
typedef __attribute__((ext_vector_type(8))) short short8;      // 8 bf16 = 4 VGPRs
typedef __attribute__((ext_vector_type(4))) float f32x4;       // MFMA C/D

__device__ __forceinline__ float fast_tanh(float x) {
    // tanh(x) = 1 - 2/(e^{2x}+1); v_rcp_f32 (1 ulp) instead of precise div.
    float e = __expf(2.0f * x);
    return 1.0f - 2.0f * __builtin_amdgcn_rcpf(e + 1.0f);
}
__device__ __forceinline__ float rowdy_act(float x, float a, float w) {
    return fast_tanh(x) + a * __sinf(w * x);
}
__device__ __forceinline__ ushort_t f32_to_bf16_rn(float f) {
    unsigned u = __float_as_uint(f);
    unsigned r = (u + 0x7FFFu + ((u >> 16) & 1u)) >> 16;
    return (ushort_t)r;
}
__device__ __forceinline__ float bf16_to_f32(ushort_t u) {
    return __uint_as_float(((unsigned)u) << 16);
}

// XOR bank-swizzle for the xfh/xfl tiles (see round-1 derivation).
//   short index: s ^ ((s>>3)&0x18);  16B-vector index: v ^ ((v>>3)&3)
// swzs(8v+k) == 8*swzv(v)+k, so b128 and b16 accesses stay consistent.
__device__ __forceinline__ int swzv(int v) { return v ^ ((v >> 3) & 3); }
__device__ __forceinline__ int swzs(int s) { return s ^ ((s >> 3) & 0x18); }

// ============ Fused prep (blocks 0-2) + branch (blocks 3-18) ============
// (unchanged — known good since round 1)
__global__ __launch_bounds__(256, 1) void prep_branch_kernel(
    const float* __restrict__ Wt, ushort_t* __restrict__ whi, ushort_t* __restrict__ wlo,
    const float* __restrict__ params, const float* __restrict__ Wb0, const float* __restrict__ bb0,
    const float* __restrict__ Wb, const float* __restrict__ bbv,
    const float* __restrict__ Wbf, const float* __restrict__ bbf,
    const float* __restrict__ ab, const float* __restrict__ wb,
    const float* __restrict__ Wtf, const float* __restrict__ btf,
    float* __restrict__ g_gates, float* __restrict__ g_wcomb, float* __restrict__ g_bcomb)
{
    __shared__ __align__(16) float wsh[HID * HID];   // 64 KB (prep staging)
    __shared__ __align__(16) float hbuf[HID];
    __shared__ __align__(16) float pred[8 * HID];    // 8-way k-split partials
    __shared__ __align__(16) float bcbuf[NOUT * HID];
    __shared__ __align__(16) float wcred[2 * NOUT * HID];
    __shared__ __align__(16) float btfs[HID];
    __shared__ float bred[NOUT][2];

    const int tid = threadIdx.x;

    if (blockIdx.x < 3) {
        // ---------------- prep: one block per trunk layer ----------------
        const int l = blockIdx.x;
        const float4* src = (const float4*)(Wt + l * HID * HID);
        #pragma unroll
        for (int i = 0; i < 16; i++)
            ((float4*)wsh)[i * 256 + tid] = src[i * 256 + tid];
        __syncthreads();
        for (int e = tid; e < 2048; e += 256) {
            int t = e >> 8, s = (e >> 6) & 3, lam = e & 63;
            int k0 = s * 32 + (lam >> 4) * 8;
            int n = t * 16 + (lam & 15);
            short8 h8, l8;
            #pragma unroll
            for (int j = 0; j < 8; j++) {
                float v = wsh[(k0 + j) * HID + n];
                ushort_t h = f32_to_bf16_rn(v);
                float rem = v - bf16_to_f32(h);
                h8[j] = (short)h;
                l8[j] = (short)f32_to_bf16_rn(rem);
            }
            ((short8*)whi)[l * 2048 + e] = h8;
            ((short8*)wlo)[l * 2048 + e] = l8;
        }
        return;
    }

    // ---------------- branch: one block per batch ----------------
    const int b = blockIdx.x - 3;
    const int j = tid & 127;
    const bool act = (tid < 128);
    const int jg = tid & 31;
    const int ks = tid >> 5;
    const int wv = tid >> 6;                 // wave id 0..3

    float abr[4], wbr[4];
    #pragma unroll
    for (int l = 0; l < 4; l++) { abr[l] = ab[l * HID + j]; wbr[l] = wb[l * HID + j]; }
    float bb0r = bb0[j];
    float bbvr[3];
    #pragma unroll
    for (int i = 0; i < 3; i++) bbvr[i] = bbv[i * HID + j];
    float bbfr[NOUT];
    #pragma unroll
    for (int o = 0; o < NOUT; o++) bbfr[o] = bbf[o * HID + j];
    float p6[6], w0r[6];
    #pragma unroll
    for (int k = 0; k < 6; k++) { p6[k] = params[b * 6 + k]; w0r[k] = Wb0[k * HID + j]; }
    if (act) btfs[j] = btf[j];

    float4 A[16], Bv[16];
    {   // prefetch layer-0 (Wb[0]) into A before L0 compute
        const float4* W4 = (const float4*)Wb;
        #pragma unroll
        for (int kk = 0; kk < 16; kk++) A[kk] = W4[(ks * 16 + kk) * 32 + jg];
    }

    // L0 (K=6)
    float g;
    {
        float z = bb0r;
        #pragma unroll
        for (int k = 0; k < 6; k++) z += p6[k] * w0r[k];
        float h = rowdy_act(z, abr[0], wbr[0]);
        if (act) { g_gates[b * 4 * HID + j] = h; hbuf[j] = h; }
        g = h;
    }
    __syncthreads();

#define BR_LAYER(CUR, I) { \
        float4 acc = make_float4(0.f, 0.f, 0.f, 0.f); \
        _Pragma("unroll") \
        for (int kk = 0; kk < 16; kk++) { \
            float hv = hbuf[ks * 16 + kk]; \
            acc.x += hv * CUR[kk].x; acc.y += hv * CUR[kk].y; \
            acc.z += hv * CUR[kk].z; acc.w += hv * CUR[kk].w; \
        } \
        *(float4*)&pred[ks * HID + 4 * jg] = acc; \
        __syncthreads(); \
        if (act) { \
            float zz = bbvr[I]; \
            _Pragma("unroll") \
            for (int s = 0; s < 8; s++) zz += pred[s * HID + j]; \
            float hn = rowdy_act(zz, abr[(I) + 1], wbr[(I) + 1]); \
            g += hn; \
            g_gates[b * 4 * HID + ((I) + 1) * HID + j] = g; \
            hbuf[j] = hn; \
        } \
        __syncthreads(); }

#define BR_CHUNK(CUR, O) { \
        float4 acc = make_float4(0.f, 0.f, 0.f, 0.f); \
        _Pragma("unroll") \
        for (int kk = 0; kk < 16; kk++) { \
            float hv = hbuf[ks * 16 + kk]; \
            acc.x += hv * CUR[kk].x; acc.y += hv * CUR[kk].y; \
            acc.z += hv * CUR[kk].z; acc.w += hv * CUR[kk].w; \
        } \
        *(float4*)&pred[ks * HID + 4 * jg] = acc; \
        __syncthreads(); \
        if (act) { \
            float s = bbfr[O]; \
            _Pragma("unroll") \
            for (int sI = 0; sI < 8; sI++) s += pred[sI * HID + j]; \
            bcbuf[(O) * HID + j] = s; \
            float pp = btfs[j] * s; \
            _Pragma("unroll") \
            for (int off = 32; off >= 1; off >>= 1) pp += __shfl_xor(pp, off, 64); \
            if ((tid & 63) == 0) bred[O][wv] = pp; \
        } \
        __syncthreads(); }

#define PF_WB(DST, I) { const float4* W4 = (const float4*)(Wb + (I) * HID * HID); \
        _Pragma("unroll") \
        for (int kk = 0; kk < 16; kk++) DST[kk] = W4[(ks * 16 + kk) * 32 + jg]; }
#define PF_BF(DST, O) { const float4* W4 = (const float4*)Wbf; \
        _Pragma("unroll") \
        for (int kk = 0; kk < 16; kk++) DST[kk] = W4[(ks * 16 + kk) * 160 + (O) * 32 + jg]; }

    PF_WB(Bv, 1)  BR_LAYER(A, 0)
    PF_WB(A, 2)   BR_LAYER(Bv, 1)
    PF_BF(Bv, 0)  BR_LAYER(A, 2)

    PF_BF(A, 1)   BR_CHUNK(Bv, 0)
    PF_BF(Bv, 2)  BR_CHUNK(A, 1)
    PF_BF(A, 3)   BR_CHUNK(Bv, 2)
    PF_BF(Bv, 4)  BR_CHUNK(A, 3)
    const int jj = tid & 127;
    const int hs = tid >> 7;                 // 0/1 half of h
    {
        const float4* Wtf4 = (const float4*)Wtf;
        #pragma unroll
        for (int kk = 0; kk < 16; kk++) A[kk] = Wtf4[jj * 32 + hs * 16 + kk];
    }
    BR_CHUNK(Bv, 4)

    {
        float wc[NOUT] = {0.f, 0.f, 0.f, 0.f, 0.f};
        #pragma unroll
        for (int h4 = 0; h4 < 16; h4++) {
            float4 wvv = A[h4];
            int h2 = hs * 64 + h4 * 4;
            #pragma unroll
            for (int o = 0; o < NOUT; o++) {
                float4 bv = *(const float4*)&bcbuf[o * HID + h2];
                wc[o] += wvv.x * bv.x + wvv.y * bv.y + wvv.z * bv.z + wvv.w * bv.w;
            }
        }
        #pragma unroll
        for (int o = 0; o < NOUT; o++) wcred[(hs * NOUT + o) * HID + jj] = wc[o];
        __syncthreads();
        if (act) {
            #pragma unroll
            for (int o = 0; o < NOUT; o++)
                g_wcomb[b * HID * NOUT + jj * NOUT + o] =
                    wcred[o * HID + jj] + wcred[(NOUT + o) * HID + jj];
        }
        if (tid < NOUT) g_bcomb[b * NOUT + tid] = bred[tid][0] + bred[tid][1];
    }
#undef BR_LAYER
#undef BR_CHUNK
#undef PF_WB
#undef PF_BF
}

// ============ Trunk kernel: LDS-cut occupancy push, NO register cap ============
// Round-2 failed nondeterministically with __launch_bounds__(256,4): the
// 128-VGPR cap forced scratch spills (L0 holds ~64 transient floats), and
// spilled kernels under hipGraph capture are a known tripwire. This round:
// identical LDS-cut structure but __launch_bounds__(256,3) (168-VGPR budget,
// no spills). Occupancy comes from LDS alone: 36,352 B -> 4 blocks/CU if
// natural VGPR <= 128. Per-layer epilogue constants loaded directly from
// global inside the fully-unrolled layer loop (no persistent arrays).
__global__ __launch_bounds__(TPB, 3) void trunk_kernel(
    const float* __restrict__ coords, const float* __restrict__ sdf,
    const float* __restrict__ Wt0, const float* __restrict__ bt0,
    const float* __restrict__ bt, const float* __restrict__ at, const float* __restrict__ wt,
    const float* __restrict__ g_gates, const float* __restrict__ g_wcomb,
    const float* __restrict__ g_bcomb,
    const ushort_t* __restrict__ whi, const ushort_t* __restrict__ wlo,
    float* __restrict__ out)
{
    __shared__ __align__(16) ushort_t xfh[TM * HID];            // 16 KB bf16 hi (swizzled)
    __shared__ __align__(16) ushort_t xfl[TM * HID];            // 16 KB bf16 lo (swizzled)
    __shared__ __align__(16) float Wc[NOUT][HID];               // 2.5 KB
    __shared__ __align__(16) float xin[TM][4];                  // 1 KB

    const int b = blockIdx.y;
    const int p0 = blockIdx.x * TM;
    const int tid = threadIdx.x;
    const int w = tid >> 6;
    const int lam = tid & 63;
    const int quad = lam >> 4, lq = lam & 15;
    const int n0 = 32 * w + lq, n1 = 32 * w + 16 + lq;

    // ---- cooperative LDS loads: Wc + xin ----
    for (int idx = tid; idx < HID * NOUT; idx += TPB) {
        int k = idx / NOUT, o = idx - k * NOUT;
        Wc[o][k] = g_wcomb[b * HID * NOUT + idx];
    }
    if (tid < 192) {
        int p = tid / 3, c = tid - p * 3;
        int gp = p0 + p;
        xin[p][c] = (gp < NPTS) ? coords[(size_t)(b * NPTS + gp) * 3 + c] : 0.0f;
    } else {
        int p = tid - 192;
        int gp = p0 + p;
        xin[p][3] = (gp < NPTS) ? sdf[b * NPTS + gp] : 0.0f;
    }
    __syncthreads();

    // ---- L0: 8 columns per thread, params from global (L2-broadcast) ----
    {
        const int col0 = w * 32 + quad * 8;
        float w0c[8], w1c[8], w2c[8], w3c[8], bc8[8], ac[8], wc8[8], gc[8];
        *(float4*)&w0c[0] = *(const float4*)&Wt0[0 * HID + col0];
        *(float4*)&w0c[4] = *(const float4*)&Wt0[0 * HID + col0 + 4];
        *(float4*)&w1c[0] = *(const float4*)&Wt0[1 * HID + col0];
        *(float4*)&w1c[4] = *(const float4*)&Wt0[1 * HID + col0 + 4];
        *(float4*)&w2c[0] = *(const float4*)&Wt0[2 * HID + col0];
        *(float4*)&w2c[4] = *(const float4*)&Wt0[2 * HID + col0 + 4];
        *(float4*)&w3c[0] = *(const float4*)&Wt0[3 * HID + col0];
        *(float4*)&w3c[4] = *(const float4*)&Wt0[3 * HID + col0 + 4];
        *(float4*)&bc8[0] = *(const float4*)&bt0[col0];
        *(float4*)&bc8[4] = *(const float4*)&bt0[col0 + 4];
        *(float4*)&ac[0]  = *(const float4*)&at[col0];
        *(float4*)&ac[4]  = *(const float4*)&at[col0 + 4];
        *(float4*)&wc8[0] = *(const float4*)&wt[col0];
        *(float4*)&wc8[4] = *(const float4*)&wt[col0 + 4];
        *(float4*)&gc[0]  = *(const float4*)&g_gates[b * 4 * HID + col0];
        *(float4*)&gc[4]  = *(const float4*)&g_gates[b * 4 * HID + col0 + 4];
        #pragma unroll
        for (int mt = 0; mt < 4; mt++) {
            int row = mt * 16 + lq;
            float4 xi = *(const float4*)&xin[row][0];
            float y[8];
            #pragma unroll
            for (int jjj = 0; jjj < 8; jjj++) {
                float zv = xi.x * w0c[jjj] + xi.y * w1c[jjj] + xi.z * w2c[jjj] + xi.w * w3c[jjj] + bc8[jjj];
                y[jjj] = rowdy_act(zv, ac[jjj], wc8[jjj]) * gc[jjj];
            }
            uint4 hp, lp;
            unsigned* hpp = (unsigned*)&hp;
            unsigned* lpp = (unsigned*)&lp;
            #pragma unroll
            for (int pr = 0; pr < 4; pr++) {
                unsigned ue = __float_as_uint(y[2 * pr]);
                unsigned uo = __float_as_uint(y[2 * pr + 1]);
                hpp[pr] = (ue >> 16) | (uo & 0xFFFF0000u);
                float le = y[2 * pr] - __uint_as_float(ue & 0xFFFF0000u);
                float lo_ = y[2 * pr + 1] - __uint_as_float(uo & 0xFFFF0000u);
                lpp[pr] = (__float_as_uint(le) >> 16) | (__float_as_uint(lo_) & 0xFFFF0000u);
            }
            int vdst = swzv((mt * 4 + w) * 64 + lam) * 8;
            *(uint4*)&xfh[vdst] = hp;
            *(uint4*)&xfl[vdst] = lp;
        }
    }
    __syncthreads();

    const short8* Wh8 = (const short8*)whi;
    const short8* Wl8 = (const short8*)wlo;
    const int lq3 = lq >> 3;
    const int jlow = lq & 7;
    const int ebase0 = w * 512 + (lq3 * 16 + quad * 4) * 8 + jlow;          // nt = 2w
    const int ebase1 = w * 512 + ((2 + lq3) * 16 + quad * 4) * 8 + jlow;    // nt = 2w+1

    #pragma unroll
    for (int l = 1; l <= 3; l++) {
        const int fb = (l - 1) * 32;
        // per-layer epilogue constants: direct global loads (l static after
        // unroll -> no arrays, no runtime indexing, minimal register life)
        float b0 = bt[(l - 1) * HID + n0], b1 = bt[(l - 1) * HID + n1];
        float a0 = at[l * HID + n0],       a1 = at[l * HID + n1];
        float ww0 = wt[l * HID + n0],      ww1 = wt[l * HID + n1];
        float gg0 = g_gates[b * 4 * HID + l * HID + n0];
        float gg1 = g_gates[b * 4 * HID + l * HID + n1];
        f32x4 acc[4][2];
        #pragma unroll
        for (int mt = 0; mt < 4; mt++) {
            acc[mt][0] = (f32x4){b0, b0, b0, b0};
            acc[mt][1] = (f32x4){b1, b1, b1, b1};
        }
        for (int s = 0; s < 4; s++) {
            short8 bh0 = Wh8[(size_t)(fb + (2 * w) * 4 + s) * 64 + lam];
            short8 bl0 = Wl8[(size_t)(fb + (2 * w) * 4 + s) * 64 + lam];
            short8 bh1 = Wh8[(size_t)(fb + (2 * w + 1) * 4 + s) * 64 + lam];
            short8 bl1 = Wl8[(size_t)(fb + (2 * w + 1) * 4 + s) * 64 + lam];
            #pragma unroll
            for (int mt = 0; mt < 4; mt++) {
                int vsrc = swzv((mt * 4 + s) * 64 + lam) * 8;
                short8 ah = *(const short8*)&xfh[vsrc];
                short8 al = *(const short8*)&xfl[vsrc];
                acc[mt][0] = __builtin_amdgcn_mfma_f32_16x16x32_bf16(ah, bh0, acc[mt][0], 0, 0, 0);
                acc[mt][0] = __builtin_amdgcn_mfma_f32_16x16x32_bf16(al, bh0, acc[mt][0], 0, 0, 0);
                acc[mt][0] = __builtin_amdgcn_mfma_f32_16x16x32_bf16(ah, bl0, acc[mt][0], 0, 0, 0);
                acc[mt][1] = __builtin_amdgcn_mfma_f32_16x16x32_bf16(ah, bh1, acc[mt][1], 0, 0, 0);
                acc[mt][1] = __builtin_amdgcn_mfma_f32_16x16x32_bf16(al, bh1, acc[mt][1], 0, 0, 0);
                acc[mt][1] = __builtin_amdgcn_mfma_f32_16x16x32_bf16(ah, bl1, acc[mt][1], 0, 0, 0);
            }
        }
        __syncthreads();
        #pragma unroll
        for (int mt = 0; mt < 4; mt++) {
            #pragma unroll
            for (int r = 0; r < 4; r++) {
                float y0 = rowdy_act(acc[mt][0][r], a0, ww0) * gg0;
                float y1 = rowdy_act(acc[mt][1][r], a1, ww1) * gg1;
                unsigned u0 = __float_as_uint(y0);
                unsigned u1 = __float_as_uint(y1);
                float l0f = y0 - __uint_as_float(u0 & 0xFFFF0000u);
                float l1f = y1 - __uint_as_float(u1 & 0xFFFF0000u);
                int i0 = swzs(mt * 2048 + ebase0 + r * 8);
                int i1 = swzs(mt * 2048 + ebase1 + r * 8);
                xfh[i0] = (ushort_t)(u0 >> 16);
                xfl[i0] = (ushort_t)(__float_as_uint(l0f) >> 16);
                xfh[i1] = (ushort_t)(u1 >> 16);
                xfl[i1] = (ushort_t)(__float_as_uint(l1f) >> 16);
            }
        }
        __syncthreads();
    }

    // ---- final contraction: per-thread partials, 4-lane shuffle reduce ----
    {
        int q = tid & 3, p = tid >> 2;
        int mt = p >> 4, prow = p & 15;
        float part[NOUT] = {0.f, 0.f, 0.f, 0.f, 0.f};
        #pragma unroll
        for (int g8 = 0; g8 < 4; g8++) {
            int base = swzv((mt * 4 + q) * 64 + g8 * 16 + prow) * 8;
            uint4 h4 = *(const uint4*)&xfh[base];
            uint4 l4 = *(const uint4*)&xfl[base];
            const unsigned* hu = (const unsigned*)&h4;
            const unsigned* lu = (const unsigned*)&l4;
            int c0 = q * 32 + g8 * 8;
            float xv[8];
            #pragma unroll
            for (int pr = 0; pr < 4; pr++) {
                xv[2 * pr]     = __uint_as_float(hu[pr] << 16) + __uint_as_float(lu[pr] << 16);
                xv[2 * pr + 1] = __uint_as_float(hu[pr] & 0xFFFF0000u) + __uint_as_float(lu[pr] & 0xFFFF0000u);
            }
            #pragma unroll
            for (int o = 0; o < NOUT; o++) {
                float4 wa = *(const float4*)&Wc[o][c0];
                float4 wb4 = *(const float4*)&Wc[o][c0 + 4];
                part[o] += xv[0] * wa.x + xv[1] * wa.y + xv[2] * wa.z + xv[3] * wa.w
                         + xv[4] * wb4.x + xv[5] * wb4.y + xv[6] * wb4.z + xv[7] * wb4.w;
            }
        }
        // q = tid&3 are adjacent lanes: butterfly over lane^1, lane^2
        #pragma unroll
        for (int o = 0; o < NOUT; o++) {
            part[o] += __shfl_xor(part[o], 1, 64);
            part[o] += __shfl_xor(part[o], 2, 64);
        }
        if (q == 0) {
            int gp = p0 + p;
            if (gp < NPTS) {
                #pragma unroll
                for (int o = 0; o < NOUT; o++)
                    out[(size_t)(b * NPTS + gp) * NOUT + o] = part[o] + g_bcomb[b * NOUT + o];
            }
        }
    }
}

extern "C" void kernel_launch(void* const* d_in, const int* in_sizes, int n_in,
                              void* d_out, int out_size, void* d_ws, size_t ws_size,
                              hipStream_t stream) {
    (void)in_sizes; (void)n_in; (void)out_size; (void)ws_size;
    const float* coords = (const float*)d_in[0];
    const float* sdf    = (const float*)d_in[1];
    const float* params = (const float*)d_in[2];
    const float* Wb0    = (const float*)d_in[3];
    const float* bb0    = (const float*)d_in[4];
    const float* Wb     = (const float*)d_in[5];
    const float* bbv    = (const float*)d_in[6];
    const float* Wbf    = (const float*)d_in[7];
    const float* bbf    = (const float*)d_in[8];
    const float* ab     = (const float*)d_in[9];
    const float* wb     = (const float*)d_in[10];
    const float* Wt0    = (const float*)d_in[11];
    const float* bt0    = (const float*)d_in[12];
    const float* Wt     = (const float*)d_in[13];
    const float* bt     = (const float*)d_in[14];
    const float* Wtf    = (const float*)d_in[15];
    const float* btf    = (const float*)d_in[16];
    const float* at     = (const float*)d_in[17];
    const float* wt     = (const float*)d_in[18];
    float* out = (float*)d_out;
    float* ws  = (float*)d_ws;

    float* g_gates = ws;                        // 8192 floats
    float* g_wcomb = ws + 8192;                 // 10240 floats
    float* g_bcomb = ws + 8192 + 10240;         // 80 floats
    ushort_t* whi = (ushort_t*)(ws + 18512);    // 49152 bf16
    ushort_t* wlo = whi + 3 * HID * HID;        // 49152 bf16

    hipLaunchKernelGGL(prep_branch_kernel, dim3(19), dim3(256), 0, stream,
                       Wt, whi, wlo,
                       params, Wb0, bb0, Wb, bbv, Wbf, bbf, ab, wb, Wtf, btf,
                       g_gates, g_wcomb, g_bcomb);

    dim3 grid((NPTS + TM - 1) / TM, BATCH);
    hipLaunchKernelGGL(trunk_kernel, grid, dim3(TPB), 0, stream,
                       coords, sdf, Wt0, bt0, bt, at, wt,
                       g_gates, g_wcomb, g_bcomb, whi, wlo, out);
}